// Round 1
// 2297.679 us; speedup vs baseline: 1.7947x; 1.7947x over previous
//
#include <hip/hip_runtime.h>
#include <hip/hip_bf16.h>

typedef __hip_bfloat16 bf16;

#define NN 30000
#define NE 480000
#define DD 128
#define ED 64
#define NH 8

// stats layout (float words) at ws offset 0
#define ST_SUM_H1 0
#define ST_SQ_H1  128
#define ST_SUM_H2 256
#define ST_SQ_H2  384
#define ST_SUM_E1 512
#define ST_SQ_E1  576
#define ST_SUM_E2 640
#define ST_SQ_E2  704
#define W_FLAG    768     // int: 1 = float inputs are bf16-packed, 0 = f32

// ws layout in 4-byte words (total 7,921,024 words = 31.7 MB)
#define W_Z     1024                  // z: N*8 f32            [zeroed]
#define W_HATT  241024                // hatt: N*128 f32       [zeroed]
#define W_SC    4081024               // score: E*8 f32
#define W_ZERO_WORDS 4081024          // stats+flag+pad+z+hatt in one memset

__device__ __forceinline__ float ldf(const void* p, long i, bool bf) {
  if (bf) return __bfloat162float(((const bf16*)p)[i]);
  return ((const float*)p)[i];
}

// ---------------- K0: detect input dtype from x ----------------
__global__ __launch_bounds__(64) void k_detect(const void* __restrict__ x, int* __restrict__ flag)
{
  int lane = threadIdx.x;
  unsigned w = ((const unsigned*)x)[lane];
  unsigned low = w & 0xFFFFu;
  unsigned el = (low >> 7) & 0xFFu;      // bf16 exponent field of low half-word
  bool hit = (el >= 0x70u && el <= 0x86u);
  unsigned long long m = __ballot(hit);
  if (lane == 0) *flag = (__popcll(m) >= 32) ? 1 : 0;
}

// ---------------- K1: Q,K,V = x @ {Wq,Wk,Wv} -> f32 (staged in d_out) ----------------
__global__ __launch_bounds__(128) void k_qkv(
    const void* __restrict__ x, const void* __restrict__ Wq,
    const void* __restrict__ Wk, const void* __restrict__ Wv,
    float* __restrict__ Q, float* __restrict__ Kb, float* __restrict__ V,
    const int* __restrict__ flag)
{
  const bool isbf = (*flag != 0);
  __shared__ float xs[128][36];   // xs[feature][row]
  int tid = threadIdx.x;
  int row0 = blockIdx.x * 32;
  int nrows = min(32, NN - row0);
  for (int r = 0; r < 32; ++r)
    xs[tid][r] = (r < nrows) ? ldf(x, (long)(row0 + r) * DD + tid, isbf) : 0.f;
  __syncthreads();
  const void* Ws[3] = {Wq, Wk, Wv};
  float* Os[3] = {Q, Kb, V};
  for (int m = 0; m < 3; ++m) {
    const void* W = Ws[m];
    float acc[32];
    #pragma unroll
    for (int r = 0; r < 32; ++r) acc[r] = 0.f;
    #pragma unroll 4
    for (int k = 0; k < 128; ++k) {
      float w = ldf(W, (long)k * DD + tid, isbf);
      const float4* xp = (const float4*)&xs[k][0];
      #pragma unroll
      for (int r4 = 0; r4 < 8; ++r4) {
        float4 x4 = xp[r4];
        acc[r4*4+0] += x4.x * w; acc[r4*4+1] += x4.y * w;
        acc[r4*4+2] += x4.z * w; acc[r4*4+3] += x4.w * w;
      }
    }
    float* O = Os[m];
    for (int r = 0; r < nrows; ++r) O[(row0 + r) * DD + tid] = acc[r];
  }
}

// ---------------- K2: per-edge scores (Pe fused), z atomic ----------------
__global__ __launch_bounds__(256) void k_edge_score(
    const int* __restrict__ ei, const void* __restrict__ ea,
    const void* __restrict__ We, const float* __restrict__ Q,
    const float* __restrict__ Kb,
    float* __restrict__ score, float* __restrict__ z,
    const int* __restrict__ flag)
{
  const bool isbf = (*flag != 0);
  int lane = threadIdx.x & 63;
  int wv = threadIdx.x >> 6;
  float w0[64], w1[64];   // We columns 2*lane, 2*lane+1
  #pragma unroll
  for (int k = 0; k < 64; ++k) {
    w0[k] = ldf(We, (long)k * DD + 2 * lane, isbf);
    w1[k] = ldf(We, (long)k * DD + 2 * lane + 1, isbf);
  }
  int nwaves = gridDim.x * 4;
  for (int e = blockIdx.x * 4 + wv; e < NE; e += nwaves) {
    int s = ei[e], d = ei[NE + e];
    float ea_l = ldf(ea, (long)e * ED + lane, isbf);
    float pe0 = 0.f, pe1 = 0.f;
    #pragma unroll
    for (int k = 0; k < 64; ++k) {
      float a = __shfl(ea_l, k);
      pe0 += a * w0[k];
      pe1 += a * w1[k];
    }
    float2 q = *(const float2*)(Q + d * DD + 2 * lane);
    float2 kk = *(const float2*)(Kb + s * DD + 2 * lane);
    float sv = q.x * kk.x * pe0 + q.y * kk.y * pe1;  // head = lane>>3
    sv += __shfl_xor(sv, 1);
    sv += __shfl_xor(sv, 2);
    sv += __shfl_xor(sv, 4);
    float scor = sv * 0.25f;   // 1/sqrt(16)
    if ((lane & 7) == 0) {
      int h = lane >> 3;
      score[e * NH + h] = scor;
      float ec = __expf(fminf(fmaxf(scor, -5.f), 5.f));
      atomicAdd(&z[d * NH + h], ec);
    }
  }
}

// ---------------- K3: aggregate msg = V[src]*alpha into h_attn ----------------
__global__ __launch_bounds__(256) void k_aggregate(
    const int* __restrict__ ei, const float* __restrict__ V,
    const float* __restrict__ score, const float* __restrict__ z,
    float* __restrict__ hatt)
{
  int lane = threadIdx.x & 63;
  int wv = threadIdx.x >> 6;
  int e = blockIdx.x * 4 + wv;
  if (e >= NE) return;
  int s = ei[e], d = ei[NE + e];
  float scv = 0.f, zv = 1.f;
  if (lane < NH) { scv = score[e * NH + lane]; zv = z[d * NH + lane]; }
  float ec = __expf(fminf(fmaxf(scv, -5.f), 5.f));
  int h = lane >> 3;
  float a = __shfl(ec, h) / (__shfl(zv, h) + 1e-6f);
  float2 v = *(const float2*)(V + s * DD + 2 * lane);
  atomicAdd(&hatt[d * DD + 2 * lane], v.x * a);
  atomicAdd(&hatt[d * DD + 2 * lane + 1], v.y * a);
}

// ---------------- K4: e1 = ea + (score@W_ep + b_ep)@W_Oe + b_Oe -> d_out f32, + stats ----------------
__global__ __launch_bounds__(256) void k_edge_proj(
    const void* __restrict__ ea, const float* __restrict__ score,
    const void* __restrict__ W_ep, const void* __restrict__ b_ep,
    const void* __restrict__ W_Oe, const void* __restrict__ b_Oe,
    float* __restrict__ eout, float* __restrict__ stats,
    const int* __restrict__ flag)
{
  const bool isbf = (*flag != 0);
  int lane = threadIdx.x & 63;
  int wv = threadIdx.x >> 6;
  float wep[8], woe[64];
  #pragma unroll
  for (int h = 0; h < 8; ++h) wep[h] = ldf(W_ep, h * ED + lane, isbf);
  #pragma unroll
  for (int k = 0; k < 64; ++k) woe[k] = ldf(W_Oe, (long)k * ED + lane, isbf);
  float bep = ldf(b_ep, lane, isbf), boe = ldf(b_Oe, lane, isbf);
  float lsum = 0.f, lsq = 0.f;
  int nwaves = gridDim.x * 4;
  for (int e = blockIdx.x * 4 + wv; e < NE; e += nwaves) {
    float scv = (lane < NH) ? score[e * NH + lane] : 0.f;
    float ep = bep;
    #pragma unroll
    for (int h = 0; h < 8; ++h) ep += __shfl(scv, h) * wep[h];
    float acc = boe;
    #pragma unroll
    for (int k = 0; k < 64; ++k) acc += __shfl(ep, k) * woe[k];
    float v = ldf(ea, (long)e * ED + lane, isbf) + acc;
    eout[(long)e * ED + lane] = v;
    lsum += v; lsq += v * v;
  }
  __shared__ float r1[4][64], r2[4][64];
  r1[wv][lane] = lsum; r2[wv][lane] = lsq;
  __syncthreads();
  if (wv == 0) {
    float s1 = r1[0][lane] + r1[1][lane] + r1[2][lane] + r1[3][lane];
    float s2 = r2[0][lane] + r2[1][lane] + r2[2][lane] + r2[3][lane];
    atomicAdd(&stats[ST_SUM_E1 + lane], s1);
    atomicAdd(&stats[ST_SQ_E1 + lane], s2);
  }
}

// ---------------- K5: h1 = x + h_attn@W_Oh + b_Oh -> d_out f32, + stats ----------------
__global__ __launch_bounds__(128) void k_hproj(
    const float* __restrict__ hatt, const void* __restrict__ x,
    const void* __restrict__ W_Oh, const void* __restrict__ b_Oh,
    float* __restrict__ hout, float* __restrict__ stats,
    const int* __restrict__ flag)
{
  const bool isbf = (*flag != 0);
  __shared__ float hs[128][36];
  int tid = threadIdx.x;
  int row0 = blockIdx.x * 32;
  int nrows = min(32, NN - row0);
  for (int r = 0; r < 32; ++r)
    hs[tid][r] = (r < nrows) ? hatt[(row0 + r) * DD + tid] : 0.f;
  __syncthreads();
  float acc[32];
  #pragma unroll
  for (int r = 0; r < 32; ++r) acc[r] = 0.f;
  #pragma unroll 4
  for (int k = 0; k < 128; ++k) {
    float w = ldf(W_Oh, (long)k * DD + tid, isbf);
    const float4* hp = (const float4*)&hs[k][0];
    #pragma unroll
    for (int r4 = 0; r4 < 8; ++r4) {
      float4 h4 = hp[r4];
      acc[r4*4+0] += h4.x * w; acc[r4*4+1] += h4.y * w;
      acc[r4*4+2] += h4.z * w; acc[r4*4+3] += h4.w * w;
    }
  }
  float bo = ldf(b_Oh, tid, isbf);
  float lsum = 0.f, lsq = 0.f;
  for (int r = 0; r < nrows; ++r) {
    float v = ldf(x, (long)(row0 + r) * DD + tid, isbf) + acc[r] + bo;
    hout[(long)(row0 + r) * DD + tid] = v;
    lsum += v; lsq += v * v;
  }
  atomicAdd(&stats[ST_SUM_H1 + tid], lsum);
  atomicAdd(&stats[ST_SQ_H1 + tid], lsq);
}

// ---------------- K6: h BN1 + FFN + residual (in-place on d_out) + stats2 ----------------
__global__ __launch_bounds__(128) void k_hffn(
    float* __restrict__ hio,
    const void* __restrict__ g1h, const void* __restrict__ B1h,
    const void* __restrict__ W_h1, const void* __restrict__ b_h1,
    const void* __restrict__ W_h2, const void* __restrict__ b_h2,
    float* __restrict__ stats, const int* __restrict__ flag)
{
  const bool isbf = (*flag != 0);
  __shared__ float hb[128][36];   // bn1 output [feature][row]
  __shared__ float uu[256][36];   // relu hidden [feature][row]
  int tid = threadIdx.x;
  int row0 = blockIdx.x * 32;
  int nrows = min(32, NN - row0);
  float m = stats[ST_SUM_H1 + tid] * (1.0f / NN);
  float var = stats[ST_SQ_H1 + tid] * (1.0f / NN) - m * m;
  float rstd = rsqrtf(fmaxf(var, 0.f) + 1e-5f);
  float g = ldf(g1h, tid, isbf), B = ldf(B1h, tid, isbf);
  for (int r = 0; r < 32; ++r) {
    float v = (r < nrows) ? hio[(long)(row0 + r) * DD + tid] : 0.f;
    hb[tid][r] = g * (v - m) * rstd + B;
  }
  __syncthreads();
  float u0[32], u1[32];
  #pragma unroll
  for (int r = 0; r < 32; ++r) { u0[r] = 0.f; u1[r] = 0.f; }
  #pragma unroll 2
  for (int k = 0; k < 128; ++k) {
    float w0 = ldf(W_h1, (long)k * 256 + tid, isbf);
    float w1 = ldf(W_h1, (long)k * 256 + 128 + tid, isbf);
    const float4* hp = (const float4*)&hb[k][0];
    #pragma unroll
    for (int r4 = 0; r4 < 8; ++r4) {
      float4 h4 = hp[r4];
      u0[r4*4+0] += h4.x * w0; u1[r4*4+0] += h4.x * w1;
      u0[r4*4+1] += h4.y * w0; u1[r4*4+1] += h4.y * w1;
      u0[r4*4+2] += h4.z * w0; u1[r4*4+2] += h4.z * w1;
      u0[r4*4+3] += h4.w * w0; u1[r4*4+3] += h4.w * w1;
    }
  }
  float bu0 = ldf(b_h1, tid, isbf), bu1 = ldf(b_h1, 128 + tid, isbf);
  for (int r = 0; r < 32; ++r) {
    uu[tid][r]       = fmaxf(u0[r] + bu0, 0.f);
    uu[128 + tid][r] = fmaxf(u1[r] + bu1, 0.f);
  }
  __syncthreads();
  float f[32];
  #pragma unroll
  for (int r = 0; r < 32; ++r) f[r] = 0.f;
  #pragma unroll 2
  for (int j = 0; j < 256; ++j) {
    float w = ldf(W_h2, (long)j * DD + tid, isbf);
    const float4* up = (const float4*)&uu[j][0];
    #pragma unroll
    for (int r4 = 0; r4 < 8; ++r4) {
      float4 u4 = up[r4];
      f[r4*4+0] += u4.x * w; f[r4*4+1] += u4.y * w;
      f[r4*4+2] += u4.z * w; f[r4*4+3] += u4.w * w;
    }
  }
  float bf2 = ldf(b_h2, tid, isbf);
  float lsum = 0.f, lsq = 0.f;
  for (int r = 0; r < nrows; ++r) {
    float t = hb[tid][r] + f[r] + bf2;
    hio[(long)(row0 + r) * DD + tid] = t;
    lsum += t; lsq += t * t;
  }
  atomicAdd(&stats[ST_SUM_H2 + tid], lsum);
  atomicAdd(&stats[ST_SQ_H2 + tid], lsq);
}

// ---------------- K7: h final BN2 in-place on d_out ----------------
__global__ __launch_bounds__(256) void k_hfinal(
    float* __restrict__ io, const void* __restrict__ g,
    const void* __restrict__ B, const float* __restrict__ stats,
    const int* __restrict__ flag)
{
  const bool isbf = (*flag != 0);
  int idx = blockIdx.x * 256 + threadIdx.x;
  int c = idx & (DD - 1);
  float m = stats[ST_SUM_H2 + c] * (1.0f / NN);
  float var = stats[ST_SQ_H2 + c] * (1.0f / NN) - m * m;
  float rstd = rsqrtf(fmaxf(var, 0.f) + 1e-5f);
  float v = io[idx];
  io[idx] = ldf(g, c, isbf) * (v - m) * rstd + ldf(B, c, isbf);
}

// ---------------- K8: e BN1 + FFN + residual (in-place on d_out) + stats2 ----------------
// Rewritten: LDS-staged tile GEMM (k_hffn structure), no per-thread weight
// arrays (old version spilled 256 floats/thread to scratch -> latency-bound,
// 2289 us, VALUBusy 14.7%). 32 edges/block, 128 threads.
__global__ __launch_bounds__(128) void k_effn(
    float* __restrict__ eio,
    const void* __restrict__ g1e, const void* __restrict__ B1e,
    const void* __restrict__ W_e1, const void* __restrict__ b_e1,
    const void* __restrict__ W_e2, const void* __restrict__ b_e2,
    float* __restrict__ stats, const int* __restrict__ flag)
{
  const bool isbf = (*flag != 0);
  __shared__ float es[64][36];    // bn1 output [feature][row], 36 keeps float4 align (144B)
  __shared__ float uu[128][36];   // relu hidden [hidden][row]
  __shared__ float rs[2][64], rq[2][64];
  int tid = threadIdx.x;
  int f = tid & 63;               // edge feature / output column
  int wv = tid >> 6;              // wave id: 0 or 1
  int rh = wv * 16;               // row half for load + 2nd GEMM
  long row0 = (long)blockIdx.x * 32;   // NE = 32 * 15000 exactly
  float m = stats[ST_SUM_E1 + f] * (1.0f / NE);
  float var = stats[ST_SQ_E1 + f] * (1.0f / NE) - m * m;
  float rstd = rsqrtf(fmaxf(var, 0.f) + 1e-5f);
  float g = ldf(g1e, f, isbf), B = ldf(B1e, f, isbf);
  #pragma unroll
  for (int r = 0; r < 16; ++r) {
    float v = eio[(row0 + rh + r) * ED + f];     // coalesced across lanes
    es[f][rh + r] = g * (v - m) * rstd + B;
  }
  __syncthreads();
  // GEMM1: u[r][j] = sum_k es[k][r] * W_e1[k][j]; thread owns hidden col j=tid
  float u[32];
  #pragma unroll
  for (int r = 0; r < 32; ++r) u[r] = 0.f;
  #pragma unroll 4
  for (int k = 0; k < 64; ++k) {
    float w = ldf(W_e1, (long)k * 128 + tid, isbf);
    const float4* ep = (const float4*)&es[k][0];   // broadcast reads
    #pragma unroll
    for (int r4 = 0; r4 < 8; ++r4) {
      float4 e4 = ep[r4];
      u[r4*4+0] += e4.x * w; u[r4*4+1] += e4.y * w;
      u[r4*4+2] += e4.z * w; u[r4*4+3] += e4.w * w;
    }
  }
  float bu = ldf(b_e1, tid, isbf);
  #pragma unroll
  for (int r = 0; r < 32; ++r) uu[tid][r] = fmaxf(u[r] + bu, 0.f);
  __syncthreads();
  // GEMM2: out[r][c] = sum_j uu[j][r] * W_e2[j][c]; thread owns col c=f, rows rh..rh+15
  float acc[16];
  #pragma unroll
  for (int r = 0; r < 16; ++r) acc[r] = 0.f;
  #pragma unroll 4
  for (int j = 0; j < 128; ++j) {
    float w = ldf(W_e2, (long)j * ED + f, isbf);
    const float4* up = (const float4*)&uu[j][rh];  // per-wave broadcast
    #pragma unroll
    for (int r4 = 0; r4 < 4; ++r4) {
      float4 u4 = up[r4];
      acc[r4*4+0] += u4.x * w; acc[r4*4+1] += u4.y * w;
      acc[r4*4+2] += u4.z * w; acc[r4*4+3] += u4.w * w;
    }
  }
  float bf2 = ldf(b_e2, f, isbf);
  float lsum = 0.f, lsq = 0.f;
  #pragma unroll
  for (int r = 0; r < 16; ++r) {
    float t = es[f][rh + r] + acc[r] + bf2;        // residual on bn1 output
    eio[(row0 + rh + r) * ED + f] = t;
    lsum += t; lsq += t * t;
  }
  rs[wv][f] = lsum; rq[wv][f] = lsq;
  __syncthreads();
  if (wv == 0) {
    atomicAdd(&stats[ST_SUM_E2 + f], rs[0][f] + rs[1][f]);
    atomicAdd(&stats[ST_SQ_E2 + f], rq[0][f] + rq[1][f]);
  }
}

// ---------------- K9: e final BN2 in-place on d_out ----------------
__global__ __launch_bounds__(256) void k_efinal(
    float* __restrict__ io, const void* __restrict__ g,
    const void* __restrict__ B, const float* __restrict__ stats,
    const int* __restrict__ flag)
{
  const bool isbf = (*flag != 0);
  int idx = blockIdx.x * 256 + threadIdx.x;
  int c = idx & (ED - 1);
  float m = stats[ST_SUM_E2 + c] * (1.0f / NE);
  float var = stats[ST_SQ_E2 + c] * (1.0f / NE) - m * m;
  float rstd = rsqrtf(fmaxf(var, 0.f) + 1e-5f);
  float v = io[idx];
  io[idx] = ldf(g, c, isbf) * (v - m) * rstd + ldf(B, c, isbf);
}

extern "C" void kernel_launch(void* const* d_in, const int* in_sizes, int n_in,
                              void* d_out, int out_size, void* d_ws, size_t ws_size,
                              hipStream_t stream) {
  const void* x    = d_in[0];
  const int*  ei   = (const int*)d_in[1];
  const void* ea   = d_in[2];
  const void* Wq   = d_in[3];
  const void* Wk   = d_in[4];
  const void* Wv   = d_in[5];
  const void* We   = d_in[6];
  const void* W_Oh = d_in[7];
  const void* b_Oh = d_in[8];
  const void* W_ep = d_in[9];
  const void* b_ep = d_in[10];
  const void* W_Oe = d_in[11];
  const void* b_Oe = d_in[12];
  const void* W_h1 = d_in[13];
  const void* b_h1 = d_in[14];
  const void* W_h2 = d_in[15];
  const void* b_h2 = d_in[16];
  const void* W_e1 = d_in[17];
  const void* b_e1 = d_in[18];
  const void* W_e2 = d_in[19];
  const void* b_e2 = d_in[20];
  const void* g1h  = d_in[21];
  const void* B1h  = d_in[22];
  const void* g1e  = d_in[23];
  const void* B1e  = d_in[24];
  const void* g2h  = d_in[25];
  const void* B2h  = d_in[26];
  const void* g2e  = d_in[27];
  const void* B2e  = d_in[28];

  float* ws    = (float*)d_ws;
  float* stats = ws;                  // 768 fl + flag
  int*   flag  = (int*)(ws + W_FLAG);
  float* z     = ws + W_Z;            // N*8 fl   [zeroed]
  float* hatt  = ws + W_HATT;         // N*128 fl [zeroed]
  float* score = ws + W_SC;           // E*8 f32
  // ws total: 31.7 MB

  // Q/K/V staged inside d_out (consumed by k_aggregate before being overwritten)
  float* out  = (float*)d_out;           // 34.56M f32 total
  float* hout = out;                     // N*128 (h staging + final)
  float* eout = out + (size_t)NN * DD;   // E*64 (e staging + final)
  float* Q    = out;                     // [0, 3.84M)
  float* Kb   = out + 3840000;           // [3.84M, 7.68M)
  float* V    = out + 7680000;           // [7.68M, 11.52M)

  hipMemsetAsync(ws, 0, (size_t)W_ZERO_WORDS * sizeof(float), stream);
  k_detect<<<1, 64, 0, stream>>>(x, flag);

  k_qkv<<<938, 128, 0, stream>>>(x, Wq, Wk, Wv, Q, Kb, V, flag);
  k_edge_score<<<1000, 256, 0, stream>>>(ei, ea, We, Q, Kb, score, z, flag);
  k_aggregate<<<120000, 256, 0, stream>>>(ei, V, score, z, hatt);
  k_edge_proj<<<1000, 256, 0, stream>>>(ea, score, W_ep, b_ep, W_Oe, b_Oe, eout, stats, flag);
  k_hproj<<<938, 128, 0, stream>>>(hatt, x, W_Oh, b_Oh, hout, stats, flag);
  k_hffn<<<938, 128, 0, stream>>>(hout, g1h, B1h, W_h1, b_h1, W_h2, b_h2, stats, flag);
  k_hfinal<<<15000, 256, 0, stream>>>(hout, g2h, B2h, stats, flag);
  k_effn<<<15000, 128, 0, stream>>>(eout, g1e, B1e, W_e1, b_e1, W_e2, b_e2, stats, flag);
  k_efinal<<<120000, 256, 0, stream>>>(eout, g2e, B2e, stats, flag);
}

// Round 2
// 2005.990 us; speedup vs baseline: 2.0556x; 1.1454x over previous
//
#include <hip/hip_runtime.h>
#include <hip/hip_bf16.h>

typedef __hip_bfloat16 bf16;

#define NN 30000
#define NE 480000
#define DD 128
#define ED 64
#define NH 8

// stats layout (float words) at ws offset 0
#define ST_SUM_H1 0
#define ST_SQ_H1  128
#define ST_SUM_H2 256
#define ST_SQ_H2  384
#define ST_SUM_E1 512
#define ST_SQ_E1  576
#define ST_SUM_E2 640
#define ST_SQ_E2  704
#define W_FLAG    768     // int: 1 = float inputs are bf16-packed, 0 = f32

// ws layout in 4-byte words (total 7,921,024 words = 31.7 MB)
#define W_Z     1024                  // z: N*8 f32            [zeroed]
#define W_HATT  241024                // hatt: N*128 f32       [zeroed]
#define W_SC    4081024               // score: E*8 f32
#define W_ZERO_WORDS 4081024          // stats+flag+pad+z+hatt in one memset

__device__ __forceinline__ float ldf(const void* p, long i, bool bf) {
  if (bf) return __bfloat162float(((const bf16*)p)[i]);
  return ((const float*)p)[i];
}

// ---------------- K0: detect input dtype from x ----------------
__global__ __launch_bounds__(64) void k_detect(const void* __restrict__ x, int* __restrict__ flag)
{
  int lane = threadIdx.x;
  unsigned w = ((const unsigned*)x)[lane];
  unsigned low = w & 0xFFFFu;
  unsigned el = (low >> 7) & 0xFFu;      // bf16 exponent field of low half-word
  bool hit = (el >= 0x70u && el <= 0x86u);
  unsigned long long m = __ballot(hit);
  if (lane == 0) *flag = (__popcll(m) >= 32) ? 1 : 0;
}

// ---------------- K1: Q,K,V = x @ {Wq,Wk,Wv} -> f32 (staged in d_out) ----------------
__global__ __launch_bounds__(128) void k_qkv(
    const void* __restrict__ x, const void* __restrict__ Wq,
    const void* __restrict__ Wk, const void* __restrict__ Wv,
    float* __restrict__ Q, float* __restrict__ Kb, float* __restrict__ V,
    const int* __restrict__ flag)
{
  const bool isbf = (*flag != 0);
  __shared__ float xs[128][36];   // xs[feature][row]
  int tid = threadIdx.x;
  int row0 = blockIdx.x * 32;
  int nrows = min(32, NN - row0);
  for (int r = 0; r < 32; ++r)
    xs[tid][r] = (r < nrows) ? ldf(x, (long)(row0 + r) * DD + tid, isbf) : 0.f;
  __syncthreads();
  const void* Ws[3] = {Wq, Wk, Wv};
  float* Os[3] = {Q, Kb, V};
  for (int m = 0; m < 3; ++m) {
    const void* W = Ws[m];
    float acc[32];
    #pragma unroll
    for (int r = 0; r < 32; ++r) acc[r] = 0.f;
    #pragma unroll 4
    for (int k = 0; k < 128; ++k) {
      float w = ldf(W, (long)k * DD + tid, isbf);
      const float4* xp = (const float4*)&xs[k][0];
      #pragma unroll
      for (int r4 = 0; r4 < 8; ++r4) {
        float4 x4 = xp[r4];
        acc[r4*4+0] += x4.x * w; acc[r4*4+1] += x4.y * w;
        acc[r4*4+2] += x4.z * w; acc[r4*4+3] += x4.w * w;
      }
    }
    float* O = Os[m];
    for (int r = 0; r < nrows; ++r) O[(row0 + r) * DD + tid] = acc[r];
  }
}

// ---------------- K2: per-edge scores (Pe fused), z atomic ----------------
// v2: tile GEMM. Old version held We cols in w0[64]+w1[64] per-thread arrays
// with VGPR_Count=84 -> scratch spill, ~15.7 TB L1/L2 traffic = 450 of its
// 464 us. New: 32 edges/block, 128 threads; ea tile in LDS, We streamed,
// pe[32] per thread feeds the Q*K*Pe reduction directly (thread = dim).
__global__ __launch_bounds__(128) void k_edge_score(
    const int* __restrict__ ei, const void* __restrict__ ea,
    const void* __restrict__ We, const float* __restrict__ Q,
    const float* __restrict__ Kb,
    float* __restrict__ score, float* __restrict__ z,
    const int* __restrict__ flag)
{
  const bool isbf = (*flag != 0);
  __shared__ float es[64][36];    // raw ea tile [feature][edge-row]
  __shared__ int sd_s[32], sd_d[32];
  int tid = threadIdx.x;
  long e0 = (long)blockIdx.x * 32;      // NE = 32 * 15000 exactly
  #pragma unroll
  for (int i = 0; i < 16; ++i) {
    int idx = i * 128 + tid;
    es[idx & 63][idx >> 6] = ldf(ea, e0 * ED + idx, isbf);   // coalesced
  }
  if (tid < 32) sd_s[tid] = ei[e0 + tid];
  else if (tid < 64) sd_d[tid - 32] = ei[NE + e0 + (tid - 32)];
  __syncthreads();
  // Pe GEMM: pe[r] = (ea @ We)[e0+r][col=tid]
  float pe[32];
  #pragma unroll
  for (int r = 0; r < 32; ++r) pe[r] = 0.f;
  #pragma unroll 4
  for (int k = 0; k < 64; ++k) {
    float w = ldf(We, (long)k * DD + tid, isbf);
    const float4* ep = (const float4*)&es[k][0];   // LDS broadcast
    #pragma unroll
    for (int r4 = 0; r4 < 8; ++r4) {
      float4 e4 = ep[r4];
      pe[r4*4+0] += e4.x * w; pe[r4*4+1] += e4.y * w;
      pe[r4*4+2] += e4.z * w; pe[r4*4+3] += e4.w * w;
    }
  }
  int h = tid >> 4;               // head 0..7 (wave0: 0-3, wave1: 4-7)
  bool lead = (tid & 15) == 0;
  #pragma unroll 4
  for (int r = 0; r < 32; ++r) {
    int s = sd_s[r], d = sd_d[r];
    float q  = Q [(long)d * DD + tid];    // coalesced 256B per wave
    float kk = Kb[(long)s * DD + tid];
    float sv = q * kk * pe[r];
    sv += __shfl_xor(sv, 1);
    sv += __shfl_xor(sv, 2);
    sv += __shfl_xor(sv, 4);
    sv += __shfl_xor(sv, 8);              // 16-lane head reduce
    if (lead) {
      float scor = sv * 0.25f;            // 1/sqrt(16)
      score[(e0 + r) * NH + h] = scor;
      float ec = __expf(fminf(fmaxf(scor, -5.f), 5.f));
      atomicAdd(&z[(long)d * NH + h], ec);
    }
  }
}

// ---------------- K3: aggregate msg = V[src]*alpha into h_attn ----------------
__global__ __launch_bounds__(256) void k_aggregate(
    const int* __restrict__ ei, const float* __restrict__ V,
    const float* __restrict__ score, const float* __restrict__ z,
    float* __restrict__ hatt)
{
  int lane = threadIdx.x & 63;
  int wv = threadIdx.x >> 6;
  int e = blockIdx.x * 4 + wv;
  if (e >= NE) return;
  int s = ei[e], d = ei[NE + e];
  float scv = 0.f, zv = 1.f;
  if (lane < NH) { scv = score[e * NH + lane]; zv = z[d * NH + lane]; }
  float ec = __expf(fminf(fmaxf(scv, -5.f), 5.f));
  int h = lane >> 3;
  float a = __shfl(ec, h) / (__shfl(zv, h) + 1e-6f);
  float2 v = *(const float2*)(V + s * DD + 2 * lane);
  atomicAdd(&hatt[d * DD + 2 * lane], v.x * a);
  atomicAdd(&hatt[d * DD + 2 * lane + 1], v.y * a);
}

// ---------------- K4: e1 = ea + (score@W_ep + b_ep)@W_Oe + b_Oe -> d_out f32, + stats ----------------
// v2: tile GEMM (32 edges/tile, grid-stride) replacing per-edge shuffle loops.
__global__ __launch_bounds__(128) void k_edge_proj(
    const void* __restrict__ ea, const float* __restrict__ score,
    const void* __restrict__ W_ep, const void* __restrict__ b_ep,
    const void* __restrict__ W_Oe, const void* __restrict__ b_Oe,
    float* __restrict__ eout, float* __restrict__ stats,
    const int* __restrict__ flag)
{
  const bool isbf = (*flag != 0);
  __shared__ float sc[32][9];      // raw scores [edge][head]
  __shared__ float ep_lds[64][36]; // ep transposed [col][edge]
  __shared__ float rs[2][64], rq[2][64];
  int tid = threadIdx.x;
  int j = tid & 63, wv = tid >> 6, rh = wv * 16;
  float bep = ldf(b_ep, j, isbf), boe = ldf(b_Oe, j, isbf);
  float wep[8];
  #pragma unroll
  for (int hh = 0; hh < 8; ++hh) wep[hh] = ldf(W_ep, hh * ED + j, isbf);
  float lsum = 0.f, lsq = 0.f;
  for (int t = blockIdx.x; t < NE / 32; t += gridDim.x) {
    long e0 = (long)t * 32;
    __syncthreads();               // prev tile's LDS reads complete
    #pragma unroll
    for (int i = 0; i < 2; ++i) {
      int idx = i * 128 + tid;
      sc[idx >> 3][idx & 7] = score[e0 * NH + idx];   // contiguous 1KB
    }
    __syncthreads();
    // ep[r][j] = b_ep[j] + sum_h sc[r][h] * W_ep[h][j]  (rows rh..rh+15)
    float u[16];
    #pragma unroll
    for (int r = 0; r < 16; ++r) u[r] = bep;
    #pragma unroll
    for (int hh = 0; hh < 8; ++hh) {
      float w = wep[hh];
      #pragma unroll
      for (int r = 0; r < 16; ++r) u[r] += sc[rh + r][hh] * w;
    }
    #pragma unroll
    for (int r = 0; r < 16; ++r) ep_lds[j][rh + r] = u[r];
    __syncthreads();
    // out[r][j] = ea[r][j] + sum_k ep[r][k] * W_Oe[k][j] + b_Oe[j]
    float acc[16];
    #pragma unroll
    for (int r = 0; r < 16; ++r) acc[r] = 0.f;
    #pragma unroll 4
    for (int k = 0; k < 64; ++k) {
      float w = ldf(W_Oe, (long)k * ED + j, isbf);
      const float4* up = (const float4*)&ep_lds[k][rh];  // broadcast
      #pragma unroll
      for (int r4 = 0; r4 < 4; ++r4) {
        float4 u4 = up[r4];
        acc[r4*4+0] += u4.x * w; acc[r4*4+1] += u4.y * w;
        acc[r4*4+2] += u4.z * w; acc[r4*4+3] += u4.w * w;
      }
    }
    #pragma unroll
    for (int r = 0; r < 16; ++r) {
      float v = ldf(ea, (e0 + rh + r) * ED + j, isbf) + acc[r] + boe;
      eout[(e0 + rh + r) * ED + j] = v;
      lsum += v; lsq += v * v;
    }
  }
  rs[wv][j] = lsum; rq[wv][j] = lsq;
  __syncthreads();
  if (wv == 0) {
    atomicAdd(&stats[ST_SUM_E1 + j], rs[0][j] + rs[1][j]);
    atomicAdd(&stats[ST_SQ_E1 + j], rq[0][j] + rq[1][j]);
  }
}

// ---------------- K5: h1 = x + h_attn@W_Oh + b_Oh -> d_out f32, + stats ----------------
__global__ __launch_bounds__(128) void k_hproj(
    const float* __restrict__ hatt, const void* __restrict__ x,
    const void* __restrict__ W_Oh, const void* __restrict__ b_Oh,
    float* __restrict__ hout, float* __restrict__ stats,
    const int* __restrict__ flag)
{
  const bool isbf = (*flag != 0);
  __shared__ float hs[128][36];
  int tid = threadIdx.x;
  int row0 = blockIdx.x * 32;
  int nrows = min(32, NN - row0);
  for (int r = 0; r < 32; ++r)
    hs[tid][r] = (r < nrows) ? hatt[(row0 + r) * DD + tid] : 0.f;
  __syncthreads();
  float acc[32];
  #pragma unroll
  for (int r = 0; r < 32; ++r) acc[r] = 0.f;
  #pragma unroll 4
  for (int k = 0; k < 128; ++k) {
    float w = ldf(W_Oh, (long)k * DD + tid, isbf);
    const float4* hp = (const float4*)&hs[k][0];
    #pragma unroll
    for (int r4 = 0; r4 < 8; ++r4) {
      float4 h4 = hp[r4];
      acc[r4*4+0] += h4.x * w; acc[r4*4+1] += h4.y * w;
      acc[r4*4+2] += h4.z * w; acc[r4*4+3] += h4.w * w;
    }
  }
  float bo = ldf(b_Oh, tid, isbf);
  float lsum = 0.f, lsq = 0.f;
  for (int r = 0; r < nrows; ++r) {
    float v = ldf(x, (long)(row0 + r) * DD + tid, isbf) + acc[r] + bo;
    hout[(long)(row0 + r) * DD + tid] = v;
    lsum += v; lsq += v * v;
  }
  atomicAdd(&stats[ST_SUM_H1 + tid], lsum);
  atomicAdd(&stats[ST_SQ_H1 + tid], lsq);
}

// ---------------- K6: h BN1 + FFN + residual (in-place on d_out) + stats2 ----------------
__global__ __launch_bounds__(128) void k_hffn(
    float* __restrict__ hio,
    const void* __restrict__ g1h, const void* __restrict__ B1h,
    const void* __restrict__ W_h1, const void* __restrict__ b_h1,
    const void* __restrict__ W_h2, const void* __restrict__ b_h2,
    float* __restrict__ stats, const int* __restrict__ flag)
{
  const bool isbf = (*flag != 0);
  __shared__ float hb[128][36];   // bn1 output [feature][row]
  __shared__ float uu[256][36];   // relu hidden [feature][row]
  int tid = threadIdx.x;
  int row0 = blockIdx.x * 32;
  int nrows = min(32, NN - row0);
  float m = stats[ST_SUM_H1 + tid] * (1.0f / NN);
  float var = stats[ST_SQ_H1 + tid] * (1.0f / NN) - m * m;
  float rstd = rsqrtf(fmaxf(var, 0.f) + 1e-5f);
  float g = ldf(g1h, tid, isbf), B = ldf(B1h, tid, isbf);
  for (int r = 0; r < 32; ++r) {
    float v = (r < nrows) ? hio[(long)(row0 + r) * DD + tid] : 0.f;
    hb[tid][r] = g * (v - m) * rstd + B;
  }
  __syncthreads();
  float u0[32], u1[32];
  #pragma unroll
  for (int r = 0; r < 32; ++r) { u0[r] = 0.f; u1[r] = 0.f; }
  #pragma unroll 2
  for (int k = 0; k < 128; ++k) {
    float w0 = ldf(W_h1, (long)k * 256 + tid, isbf);
    float w1 = ldf(W_h1, (long)k * 256 + 128 + tid, isbf);
    const float4* hp = (const float4*)&hb[k][0];
    #pragma unroll
    for (int r4 = 0; r4 < 8; ++r4) {
      float4 h4 = hp[r4];
      u0[r4*4+0] += h4.x * w0; u1[r4*4+0] += h4.x * w1;
      u0[r4*4+1] += h4.y * w0; u1[r4*4+1] += h4.y * w1;
      u0[r4*4+2] += h4.z * w0; u1[r4*4+2] += h4.z * w1;
      u0[r4*4+3] += h4.w * w0; u1[r4*4+3] += h4.w * w1;
    }
  }
  float bu0 = ldf(b_h1, tid, isbf), bu1 = ldf(b_h1, 128 + tid, isbf);
  for (int r = 0; r < 32; ++r) {
    uu[tid][r]       = fmaxf(u0[r] + bu0, 0.f);
    uu[128 + tid][r] = fmaxf(u1[r] + bu1, 0.f);
  }
  __syncthreads();
  float f[32];
  #pragma unroll
  for (int r = 0; r < 32; ++r) f[r] = 0.f;
  #pragma unroll 2
  for (int j = 0; j < 256; ++j) {
    float w = ldf(W_h2, (long)j * DD + tid, isbf);
    const float4* up = (const float4*)&uu[j][0];
    #pragma unroll
    for (int r4 = 0; r4 < 8; ++r4) {
      float4 u4 = up[r4];
      f[r4*4+0] += u4.x * w; f[r4*4+1] += u4.y * w;
      f[r4*4+2] += u4.z * w; f[r4*4+3] += u4.w * w;
    }
  }
  float bf2 = ldf(b_h2, tid, isbf);
  float lsum = 0.f, lsq = 0.f;
  for (int r = 0; r < nrows; ++r) {
    float t = hb[tid][r] + f[r] + bf2;
    hio[(long)(row0 + r) * DD + tid] = t;
    lsum += t; lsq += t * t;
  }
  atomicAdd(&stats[ST_SUM_H2 + tid], lsum);
  atomicAdd(&stats[ST_SQ_H2 + tid], lsq);
}

// ---------------- K7: h final BN2 in-place on d_out ----------------
__global__ __launch_bounds__(256) void k_hfinal(
    float* __restrict__ io, const void* __restrict__ g,
    const void* __restrict__ B, const float* __restrict__ stats,
    const int* __restrict__ flag)
{
  const bool isbf = (*flag != 0);
  int idx = blockIdx.x * 256 + threadIdx.x;
  int c = idx & (DD - 1);
  float m = stats[ST_SUM_H2 + c] * (1.0f / NN);
  float var = stats[ST_SQ_H2 + c] * (1.0f / NN) - m * m;
  float rstd = rsqrtf(fmaxf(var, 0.f) + 1e-5f);
  float v = io[idx];
  io[idx] = ldf(g, c, isbf) * (v - m) * rstd + ldf(B, c, isbf);
}

// ---------------- K8: e BN1 + FFN + residual (in-place on d_out) + stats2 ----------------
__global__ __launch_bounds__(128) void k_effn(
    float* __restrict__ eio,
    const void* __restrict__ g1e, const void* __restrict__ B1e,
    const void* __restrict__ W_e1, const void* __restrict__ b_e1,
    const void* __restrict__ W_e2, const void* __restrict__ b_e2,
    float* __restrict__ stats, const int* __restrict__ flag)
{
  const bool isbf = (*flag != 0);
  __shared__ float es[64][36];    // bn1 output [feature][row]
  __shared__ float uu[128][36];   // relu hidden [hidden][row]
  __shared__ float rs[2][64], rq[2][64];
  int tid = threadIdx.x;
  int f = tid & 63;               // edge feature / output column
  int wv = tid >> 6;              // wave id: 0 or 1
  int rh = wv * 16;               // row half for load + 2nd GEMM
  long row0 = (long)blockIdx.x * 32;   // NE = 32 * 15000 exactly
  float m = stats[ST_SUM_E1 + f] * (1.0f / NE);
  float var = stats[ST_SQ_E1 + f] * (1.0f / NE) - m * m;
  float rstd = rsqrtf(fmaxf(var, 0.f) + 1e-5f);
  float g = ldf(g1e, f, isbf), B = ldf(B1e, f, isbf);
  #pragma unroll
  for (int r = 0; r < 16; ++r) {
    float v = eio[(row0 + rh + r) * ED + f];     // coalesced across lanes
    es[f][rh + r] = g * (v - m) * rstd + B;
  }
  __syncthreads();
  // GEMM1: u[r][j] = sum_k es[k][r] * W_e1[k][j]; thread owns hidden col j=tid
  float u[32];
  #pragma unroll
  for (int r = 0; r < 32; ++r) u[r] = 0.f;
  #pragma unroll 4
  for (int k = 0; k < 64; ++k) {
    float w = ldf(W_e1, (long)k * 128 + tid, isbf);
    const float4* ep = (const float4*)&es[k][0];   // broadcast reads
    #pragma unroll
    for (int r4 = 0; r4 < 8; ++r4) {
      float4 e4 = ep[r4];
      u[r4*4+0] += e4.x * w; u[r4*4+1] += e4.y * w;
      u[r4*4+2] += e4.z * w; u[r4*4+3] += e4.w * w;
    }
  }
  float bu = ldf(b_e1, tid, isbf);
  #pragma unroll
  for (int r = 0; r < 32; ++r) uu[tid][r] = fmaxf(u[r] + bu, 0.f);
  __syncthreads();
  // GEMM2: out[r][c] = sum_j uu[j][r] * W_e2[j][c]; thread owns col c=f, rows rh..rh+15
  float acc[16];
  #pragma unroll
  for (int r = 0; r < 16; ++r) acc[r] = 0.f;
  #pragma unroll 4
  for (int j = 0; j < 128; ++j) {
    float w = ldf(W_e2, (long)j * ED + f, isbf);
    const float4* up = (const float4*)&uu[j][rh];  // per-wave broadcast
    #pragma unroll
    for (int r4 = 0; r4 < 4; ++r4) {
      float4 u4 = up[r4];
      acc[r4*4+0] += u4.x * w; acc[r4*4+1] += u4.y * w;
      acc[r4*4+2] += u4.z * w; acc[r4*4+3] += u4.w * w;
    }
  }
  float bf2 = ldf(b_e2, f, isbf);
  float lsum = 0.f, lsq = 0.f;
  #pragma unroll
  for (int r = 0; r < 16; ++r) {
    float t = es[f][rh + r] + acc[r] + bf2;        // residual on bn1 output
    eio[(row0 + rh + r) * ED + f] = t;
    lsum += t; lsq += t * t;
  }
  rs[wv][f] = lsum; rq[wv][f] = lsq;
  __syncthreads();
  if (wv == 0) {
    atomicAdd(&stats[ST_SUM_E2 + f], rs[0][f] + rs[1][f]);
    atomicAdd(&stats[ST_SQ_E2 + f], rq[0][f] + rq[1][f]);
  }
}

// ---------------- K9: e final BN2 in-place on d_out ----------------
__global__ __launch_bounds__(256) void k_efinal(
    float* __restrict__ io, const void* __restrict__ g,
    const void* __restrict__ B, const float* __restrict__ stats,
    const int* __restrict__ flag)
{
  const bool isbf = (*flag != 0);
  int idx = blockIdx.x * 256 + threadIdx.x;
  int c = idx & (ED - 1);
  float m = stats[ST_SUM_E2 + c] * (1.0f / NE);
  float var = stats[ST_SQ_E2 + c] * (1.0f / NE) - m * m;
  float rstd = rsqrtf(fmaxf(var, 0.f) + 1e-5f);
  float v = io[idx];
  io[idx] = ldf(g, c, isbf) * (v - m) * rstd + ldf(B, c, isbf);
}

extern "C" void kernel_launch(void* const* d_in, const int* in_sizes, int n_in,
                              void* d_out, int out_size, void* d_ws, size_t ws_size,
                              hipStream_t stream) {
  const void* x    = d_in[0];
  const int*  ei   = (const int*)d_in[1];
  const void* ea   = d_in[2];
  const void* Wq   = d_in[3];
  const void* Wk   = d_in[4];
  const void* Wv   = d_in[5];
  const void* We   = d_in[6];
  const void* W_Oh = d_in[7];
  const void* b_Oh = d_in[8];
  const void* W_ep = d_in[9];
  const void* b_ep = d_in[10];
  const void* W_Oe = d_in[11];
  const void* b_Oe = d_in[12];
  const void* W_h1 = d_in[13];
  const void* b_h1 = d_in[14];
  const void* W_h2 = d_in[15];
  const void* b_h2 = d_in[16];
  const void* W_e1 = d_in[17];
  const void* b_e1 = d_in[18];
  const void* W_e2 = d_in[19];
  const void* b_e2 = d_in[20];
  const void* g1h  = d_in[21];
  const void* B1h  = d_in[22];
  const void* g1e  = d_in[23];
  const void* B1e  = d_in[24];
  const void* g2h  = d_in[25];
  const void* B2h  = d_in[26];
  const void* g2e  = d_in[27];
  const void* B2e  = d_in[28];

  float* ws    = (float*)d_ws;
  float* stats = ws;                  // 768 fl + flag
  int*   flag  = (int*)(ws + W_FLAG);
  float* z     = ws + W_Z;            // N*8 fl   [zeroed]
  float* hatt  = ws + W_HATT;         // N*128 fl [zeroed]
  float* score = ws + W_SC;           // E*8 f32
  // ws total: 31.7 MB

  // Q/K/V staged inside d_out (consumed by k_aggregate before being overwritten)
  float* out  = (float*)d_out;           // 34.56M f32 total
  float* hout = out;                     // N*128 (h staging + final)
  float* eout = out + (size_t)NN * DD;   // E*64 (e staging + final)
  float* Q    = out;                     // [0, 3.84M)
  float* Kb   = out + 3840000;           // [3.84M, 7.68M)
  float* V    = out + 7680000;           // [7.68M, 11.52M)

  hipMemsetAsync(ws, 0, (size_t)W_ZERO_WORDS * sizeof(float), stream);
  k_detect<<<1, 64, 0, stream>>>(x, flag);

  k_qkv<<<938, 128, 0, stream>>>(x, Wq, Wk, Wv, Q, Kb, V, flag);
  k_edge_score<<<15000, 128, 0, stream>>>(ei, ea, We, Q, Kb, score, z, flag);
  k_aggregate<<<120000, 256, 0, stream>>>(ei, V, score, z, hatt);
  k_edge_proj<<<2048, 128, 0, stream>>>(ea, score, W_ep, b_ep, W_Oe, b_Oe, eout, stats, flag);
  k_hproj<<<938, 128, 0, stream>>>(hatt, x, W_Oh, b_Oh, hout, stats, flag);
  k_hffn<<<938, 128, 0, stream>>>(hout, g1h, B1h, W_h1, b_h1, W_h2, b_h2, stats, flag);
  k_hfinal<<<15000, 256, 0, stream>>>(hout, g2h, B2h, stats, flag);
  k_effn<<<15000, 128, 0, stream>>>(eout, g1e, B1e, W_e1, b_e1, W_e2, b_e2, stats, flag);
  k_efinal<<<120000, 256, 0, stream>>>(eout, g2e, B2e, stats, flag);
}